// Round 7
// baseline (173.414 us; speedup 1.0000x reference)
//
#include <hip/hip_runtime.h>

// GAE scan: T=2048, N=4096, fp32. 3-kernel chunked scan at C=256 + dones
// byte-mask.
//
// History: fused/barrier/lookback variants all latency-catastrophic (rounds
// 2/3/5: inter-block waits cost us-per-hop on MI355X). Multi-kernel sweep:
// C=512 -> 186.4us (fat intermediates, L=4 replay), C=128 -> 168.0us
// (8 waves/CU: ~1.9KB in-flight/CU -> latency-bound ~2-4 TB/s). This round:
// C=256 (16 waves/CU, 4MB intermediates, L=8) + byte-packed dones so K3
// reads 66MB instead of 96MB (exact: dones are exactly 0.0/1.0).
//
//   K1 gae_sum : per-(chunk, env4) affine (A,P); also packs dones bits into
//                mask[T][NV4] (2MB). 1024 blocks = 16 waves/CU.
//   K2 gae_scan: per-column suffix scan of 256 chunk affines in LDS
//                (Hillis-Steele, 8 levels). Inc[c][n4] = adv entering chunk c.
//   K3 gae_out : adv = Inc[idx], replay 8 steps reading r, v, mask (dones
//                via 1-byte mask), write advantages + returns.
// No atomics, no inter-block waiting; kernel boundaries are the only sync.

#define T_LEN    2048
#define N_ENV    4096
#define NV4      (N_ENV / 4)          // 1024 float4 columns
#define N_CHUNKS 256
#define CHUNK_L  (T_LEN / N_CHUNKS)   // 8
#define NBLK     ((N_CHUNKS * NV4) / 256)   // 1024 blocks

static constexpr float GAMMA = 0.99f;
static constexpr float GL    = 0.99f * 0.95f;   // gamma * gae_lambda

// ---- K1: per-chunk affine composition + dones bit-pack --------------------
__global__ __launch_bounds__(256) void gae_sum(
    const float4* __restrict__ rewards,   // [T_LEN][NV4]
    const float4* __restrict__ values,
    const float4* __restrict__ dones,
    float4* __restrict__ Aout,            // [N_CHUNKS][NV4]
    float4* __restrict__ Pout,
    unsigned char* __restrict__ mask)     // [T_LEN][NV4] done-bits (4/byte)
{
    const int idx = blockIdx.x * blockDim.x + threadIdx.x;   // c*NV4 + n4
    const int n4 = idx & (NV4 - 1);
    const int c  = idx >> 10;
    const int t_hi = c * CHUNK_L + (CHUNK_L - 1);

    float4 v_next, d_next;
    if (c == N_CHUNKS - 1) {
        v_next = make_float4(0.f, 0.f, 0.f, 0.f);
        d_next = make_float4(1.f, 1.f, 1.f, 1.f);
    } else {
        v_next = values[(t_hi + 1) * NV4 + n4];
        d_next = dones [(t_hi + 1) * NV4 + n4];
    }

    float4 A = make_float4(1.f, 1.f, 1.f, 1.f);
    float4 P = make_float4(0.f, 0.f, 0.f, 0.f);

    #pragma unroll
    for (int i = 0; i < CHUNK_L; ++i) {
        const int t = t_hi - i;
        const float4 r = rewards[t * NV4 + n4];
        const float4 v = values [t * NV4 + n4];
        const float4 d = dones  [t * NV4 + n4];
        const unsigned char mb =
            (unsigned char)((d.x != 0.f)      | ((d.y != 0.f) << 1) |
                            ((d.z != 0.f) << 2) | ((d.w != 0.f) << 3));
        mask[t * NV4 + n4] = mb;
        #define STEP(X) { \
            const float nt    = 1.0f - d_next.X; \
            const float delta = fmaf(GAMMA * v_next.X, nt, r.X) - v.X; \
            const float co    = GL * nt; \
            P.X = fmaf(co, P.X, delta); \
            A.X = co * A.X; \
            v_next.X = v.X; d_next.X = d.X; }
        STEP(x) STEP(y) STEP(z) STEP(w)
        #undef STEP
    }
    Aout[idx] = A;
    Pout[idx] = P;
}

// ---- K2: per-column suffix scan (proven at C=128 and C=512; 8 levels) -----
// Thread c holds f_c = (A,P); S_c = f_c o f_{c+1} o ... o f_{C-1};
// Inc[c] = S_{c+1}.P. Combine (outer o inner): (a1,p1)o(a2,p2) =
// (a1*a2, a1*p2 + p1).
__global__ __launch_bounds__(N_CHUNKS) void gae_scan(
    const float4* __restrict__ Ain,    // [N_CHUNKS][NV4]
    const float4* __restrict__ Pin,
    float4* __restrict__ Inc)          // [N_CHUNKS][NV4]
{
    __shared__ float4 sA[2][N_CHUNKS];   // 8 KB
    __shared__ float4 sP[2][N_CHUNKS];   // 8 KB
    const int n4 = blockIdx.x;
    const int c  = threadIdx.x;

    float4 a = Ain[c * NV4 + n4];
    float4 p = Pin[c * NV4 + n4];
    int cur = 0;
    sA[0][c] = a; sP[0][c] = p;
    __syncthreads();

    #pragma unroll
    for (int d = 1; d < N_CHUNKS; d <<= 1) {
        float4 na = a, np = p;
        if (c + d < N_CHUNKS) {
            const float4 a2 = sA[cur][c + d];
            const float4 p2 = sP[cur][c + d];
            na.x = a.x * a2.x;  np.x = fmaf(a.x, p2.x, p.x);
            na.y = a.y * a2.y;  np.y = fmaf(a.y, p2.y, p.y);
            na.z = a.z * a2.z;  np.z = fmaf(a.z, p2.z, p.z);
            na.w = a.w * a2.w;  np.w = fmaf(a.w, p2.w, p.w);
        }
        sA[cur ^ 1][c] = na; sP[cur ^ 1][c] = np;
        __syncthreads();
        a = na; p = np; cur ^= 1;
    }

    float4 inc = (c == N_CHUNKS - 1) ? make_float4(0.f, 0.f, 0.f, 0.f)
                                     : sP[cur][c + 1];
    Inc[c * NV4 + n4] = inc;
}

// ---- K3: replay with exact incoming advantage; dones via byte-mask --------
__global__ __launch_bounds__(256) void gae_out(
    const float4* __restrict__ rewards,
    const float4* __restrict__ values,
    const unsigned char* __restrict__ mask,
    const float4* __restrict__ Inc,
    float4* __restrict__ out)          // [2*T_LEN][NV4]: advantages, returns
{
    const int idx = blockIdx.x * blockDim.x + threadIdx.x;
    const int n4 = idx & (NV4 - 1);
    const int c  = idx >> 10;
    const int t_hi = c * CHUNK_L + (CHUNK_L - 1);

    float4 adv = Inc[idx];

    float4 v_next;
    unsigned int mb_next;
    if (c == N_CHUNKS - 1) {
        v_next  = make_float4(0.f, 0.f, 0.f, 0.f);
        mb_next = 0xFu;                       // done=1 -> nt=0 bootstrap
    } else {
        v_next  = values[(t_hi + 1) * NV4 + n4];
        mb_next = mask  [(t_hi + 1) * NV4 + n4];
    }

    #pragma unroll
    for (int i = 0; i < CHUNK_L; ++i) {
        const int t = t_hi - i;
        const float4 r = rewards[t * NV4 + n4];
        const float4 v = values [t * NV4 + n4];
        const unsigned int mb = mask[t * NV4 + n4];
        float4 ret;
        #define STEP(X, B) { \
            const float nt    = (mb_next & (B)) ? 0.0f : 1.0f; \
            const float delta = fmaf(GAMMA * v_next.X, nt, r.X) - v.X; \
            const float co    = GL * nt; \
            adv.X = fmaf(co, adv.X, delta); \
            ret.X = adv.X + v.X; \
            v_next.X = v.X; }
        STEP(x, 1u) STEP(y, 2u) STEP(z, 4u) STEP(w, 8u)
        #undef STEP
        mb_next = mb;
        out[t * NV4 + n4]           = adv;   // advantages
        out[(T_LEN + t) * NV4 + n4] = ret;   // returns
    }
}

// ---- fallback: zero-ws-dependency 2-kernel path (lookback), never expected -
__global__ __launch_bounds__(256) void gae_phase23_fb(
    const float4* __restrict__ rewards,
    const float4* __restrict__ values,
    const float4* __restrict__ dones,
    const float4* __restrict__ Ain,
    const float4* __restrict__ Pin,
    float4* __restrict__ out)
{
    const int idx = blockIdx.x * blockDim.x + threadIdx.x;
    const int n4 = idx & (NV4 - 1);
    const int c  = idx >> 10;
    const int t_hi = c * CHUNK_L + (CHUNK_L - 1);

    float4 adv = make_float4(0.f, 0.f, 0.f, 0.f);
    #pragma unroll 4
    for (int c2 = N_CHUNKS - 1; c2 > c; --c2) {
        const float4 a = Ain[c2 * NV4 + n4];
        const float4 p = Pin[c2 * NV4 + n4];
        adv.x = fmaf(a.x, adv.x, p.x);
        adv.y = fmaf(a.y, adv.y, p.y);
        adv.z = fmaf(a.z, adv.z, p.z);
        adv.w = fmaf(a.w, adv.w, p.w);
    }
    float4 v_next, d_next;
    if (c == N_CHUNKS - 1) {
        v_next = make_float4(0.f, 0.f, 0.f, 0.f);
        d_next = make_float4(1.f, 1.f, 1.f, 1.f);
    } else {
        v_next = values[(t_hi + 1) * NV4 + n4];
        d_next = dones [(t_hi + 1) * NV4 + n4];
    }
    #pragma unroll
    for (int i = 0; i < CHUNK_L; ++i) {
        const int t = t_hi - i;
        const float4 r = rewards[t * NV4 + n4];
        const float4 v = values [t * NV4 + n4];
        const float4 d = dones  [t * NV4 + n4];
        float4 ret;
        #define STEP(X) { \
            const float nt    = 1.0f - d_next.X; \
            const float delta = fmaf(GAMMA * v_next.X, nt, r.X) - v.X; \
            const float co    = GL * nt; \
            adv.X = fmaf(co, adv.X, delta); \
            ret.X = adv.X + v.X; \
            v_next.X = v.X; d_next.X = d.X; }
        STEP(x) STEP(y) STEP(z) STEP(w)
        #undef STEP
        out[t * NV4 + n4]           = adv;
        out[(T_LEN + t) * NV4 + n4] = ret;
    }
}

extern "C" void kernel_launch(void* const* d_in, const int* in_sizes, int n_in,
                              void* d_out, int out_size, void* d_ws, size_t ws_size,
                              hipStream_t stream) {
    const float4* rewards = (const float4*)d_in[0];
    const float4* values  = (const float4*)d_in[1];
    const float4* dones   = (const float4*)d_in[2];
    float4* out = (float4*)d_out;

    // Workspace: A | P | Inc (4 MiB each) | mask (2 MiB). All fully written
    // before read (0xAA poison safe). No memsets, no atomics.
    const size_t entries = (size_t)N_CHUNKS * NV4;         // 262144
    float4* A   = (float4*)d_ws;
    float4* P   = A + entries;
    float4* Inc = P + entries;
    unsigned char* mask = (unsigned char*)(Inc + entries);
    const size_t needed = 3 * entries * sizeof(float4)
                        + (size_t)T_LEN * NV4;             // +2 MiB mask

    if (ws_size >= needed) {
        gae_sum <<<NBLK, 256, 0, stream>>>(rewards, values, dones, A, P, mask);
        gae_scan<<<NV4, N_CHUNKS, 0, stream>>>(A, P, Inc);
        gae_out <<<NBLK, 256, 0, stream>>>(rewards, values, mask, Inc, out);
    } else {
        // Fallback (needs only A/P = 8 MiB): sum + O(C^2) lookback replay.
        gae_sum      <<<NBLK, 256, 0, stream>>>(rewards, values, dones, A, P, mask);
        gae_phase23_fb<<<NBLK, 256, 0, stream>>>(rewards, values, dones, A, P, out);
    }
}